// Round 3
// baseline (355.974 us; speedup 1.0000x reference)
//
#include <hip/hip_runtime.h>
#include <math.h>

typedef _Float16 v8h __attribute__((ext_vector_type(8)));
typedef float v4f __attribute__((ext_vector_type(4)));

#define UNITS    50
#define K3       150
#define FDIM     64
#define TSTEPS   128
#define BATCH    4096
#define NB       16     // batch rows per wave-tile (MFMA M)
#define H16S     72     // halves per h row (50 h + slot50=1.0 + pad; stride 144B, 16B-aligned, 2-way banks)
#define H32S     52

#if __has_builtin(__builtin_amdgcn_exp2f)
__device__ __forceinline__ float fast_exp2(float x) { return __builtin_amdgcn_exp2f(x); }
#else
__device__ __forceinline__ float fast_exp2(float x) { return exp2f(x); }
#endif
#if __has_builtin(__builtin_amdgcn_rcpf)
__device__ __forceinline__ float fast_rcp(float x) { return __builtin_amdgcn_rcpf(x); }
#else
__device__ __forceinline__ float fast_rcp(float x) { return 1.0f / x; }
#endif

// One wave per 16-batch tile. All 3 gates in-wave: Z/R/HX/HH accumulators for a
// given (m,u) land in the same lane & register slot (C layout: row=quad*4+reg,
// col=lane&15), so gate math is register-local. h f32 state lives in registers;
// only the f16 copy round-trips LDS for the A-fragment transpose.
__global__ __launch_bounds__(64, 1)
void gru_wave(const float* __restrict__ x, const float* __restrict__ W,
              const float* __restrict__ U, const float* __restrict__ bv,
              const float* __restrict__ Wd, const float* __restrict__ bd,
              float* __restrict__ out) {
    __shared__ _Float16 hs16[NB * H16S];
    __shared__ float    hs32[NB * H32S];

    const int lane = threadIdx.x;        // 0..63 (one wave)
    const int n    = lane & 15;          // col-in-tile (units) / A batch row
    const int quad = lane >> 4;
    const int b0   = blockIdx.x * NB;

    // ---- init h16 = 0, plus constant 1.0 at u=50 (feeds synthetic bias row k=114) ----
    for (int i = lane; i < NB * H16S; i += 64) hs16[i] = (_Float16)0.f;
    __syncthreads();
    if (lane < NB) hs16[lane * H16S + 50] = (_Float16)1.f;

    // ---- B fragments (all 3 gates) resident in VGPRs for the whole kernel ----
    // combined K rows: 0..63 = W rows, 64..113 = U rows, 114 = b[1] fold (h gate only), rest 0
    v8h Bz[4][4], Br[4][4], Bh[4][4];   // [ktile][ntile]
    #pragma unroll
    for (int kt = 0; kt < 4; ++kt) {
        #pragma unroll
        for (int nt = 0; nt < 4; ++nt) {
            const int c = nt * 16 + n;
            v8h fz, fr, fh;
            #pragma unroll
            for (int j = 0; j < 8; ++j) {
                const int k = kt * 32 + quad * 8 + j;
                float vz = 0.f, vr = 0.f, vh = 0.f;
                if (c < UNITS) {
                    if (k < FDIM) {
                        vz = W[k * K3 + c];
                        vr = W[k * K3 + 50 + c];
                        vh = W[k * K3 + 100 + c];
                    } else if (k < FDIM + UNITS) {
                        const int ur = k - FDIM;
                        vz = U[ur * K3 + c];
                        vr = U[ur * K3 + 50 + c];
                        vh = U[ur * K3 + 100 + c];
                    } else if (k == FDIM + UNITS) {
                        vh = bv[250 + c];            // b[1] h-col via A slot u=50 == 1.0
                    }
                }
                fz[j] = (_Float16)vz; fr[j] = (_Float16)vr; fh[j] = (_Float16)vh;
            }
            Bz[kt][nt] = fz; Br[kt][nt] = fr; Bh[kt][nt] = fh;
        }
    }

    // ---- per-ntile sigmoid-folded bias constants ----
    const float CE = -1.44269504f;       // sigmoid(a) = 1 / (1 + 2^(CE*a))
    float bzc[4], brc[4], bx4[4];
    #pragma unroll
    for (int nt = 0; nt < 4; ++nt) {
        const int c = nt * 16 + n;
        float z = 0.f, r = 0.f, xb = 0.f;
        if (c < UNITS) {
            z  = CE * (bv[c]       + bv[150 + c]);
            r  = CE * (bv[50 + c]  + bv[200 + c]);
            xb = bv[100 + c];
        }
        bzc[nt] = z; brc[nt] = r; bx4[nt] = xb;
    }

    // ---- f32 h state in registers: h32[nt][r] = h[m=quad*4+r][u=nt*16+n] ----
    v4f h32[4];
    #pragma unroll
    for (int nt = 0; nt < 4; ++nt) h32[nt] = (v4f){0.f, 0.f, 0.f, 0.f};

    // ---- x prefetch for t=0 (lane covers batch row b0+n, k=quad*8..+7, +32) ----
    const float* xb = x + ((size_t)(b0 + n) * TSTEPS) * FDIM + quad * 8;
    v4f px0 = *(const v4f*)(xb + 0);
    v4f px1 = *(const v4f*)(xb + 4);
    v4f px2 = *(const v4f*)(xb + 32);
    v4f px3 = *(const v4f*)(xb + 36);

    __syncthreads();

    for (int t = 0; t < TSTEPS; ++t) {
        // A fragments: x part from regs, h part from LDS
        v8h A0, A1;
        #pragma unroll
        for (int j = 0; j < 4; ++j) {
            A0[j]     = (_Float16)px0[j];
            A0[j + 4] = (_Float16)px1[j];
            A1[j]     = (_Float16)px2[j];
            A1[j + 4] = (_Float16)px3[j];
        }
        v8h A2 = *(const v8h*)(&hs16[n * H16S + quad * 8]);       // k 64..95  (h 0..31)
        v8h A3 = *(const v8h*)(&hs16[n * H16S + 32 + quad * 8]);  // k 96..127 (h 32..49, 1.0, 0s)

        if (t + 1 < TSTEPS) {
            const float* xp = xb + (size_t)(t + 1) * FDIM;
            px0 = *(const v4f*)(xp + 0);
            px1 = *(const v4f*)(xp + 4);
            px2 = *(const v4f*)(xp + 32);
            px3 = *(const v4f*)(xp + 36);
        }

        const v4f zero4 = (v4f){0.f, 0.f, 0.f, 0.f};
        #pragma unroll
        for (int nt = 0; nt < 4; ++nt) {
            // x-dependent MFMAs first (off critical path), then h-dependent
            v4f az = __builtin_amdgcn_mfma_f32_16x16x32_f16(A0, Bz[0][nt], zero4, 0, 0, 0);
            az     = __builtin_amdgcn_mfma_f32_16x16x32_f16(A1, Bz[1][nt], az,    0, 0, 0);
            v4f ar = __builtin_amdgcn_mfma_f32_16x16x32_f16(A0, Br[0][nt], zero4, 0, 0, 0);
            ar     = __builtin_amdgcn_mfma_f32_16x16x32_f16(A1, Br[1][nt], ar,    0, 0, 0);
            v4f ax = __builtin_amdgcn_mfma_f32_16x16x32_f16(A0, Bh[0][nt], zero4, 0, 0, 0);
            ax     = __builtin_amdgcn_mfma_f32_16x16x32_f16(A1, Bh[1][nt], ax,    0, 0, 0);
            az     = __builtin_amdgcn_mfma_f32_16x16x32_f16(A2, Bz[2][nt], az,    0, 0, 0);
            az     = __builtin_amdgcn_mfma_f32_16x16x32_f16(A3, Bz[3][nt], az,    0, 0, 0);
            ar     = __builtin_amdgcn_mfma_f32_16x16x32_f16(A2, Br[2][nt], ar,    0, 0, 0);
            ar     = __builtin_amdgcn_mfma_f32_16x16x32_f16(A3, Br[3][nt], ar,    0, 0, 0);
            v4f ah = __builtin_amdgcn_mfma_f32_16x16x32_f16(A2, Bh[2][nt], zero4, 0, 0, 0);
            ah     = __builtin_amdgcn_mfma_f32_16x16x32_f16(A3, Bh[3][nt], ah,    0, 0, 0);

            // register-local gate math: 4 rows (m = quad*4 + r)
            #pragma unroll
            for (int r = 0; r < 4; ++r) {
                const float ez = fast_exp2(fmaf(az[r], CE, bzc[nt]));
                const float er = fast_exp2(fmaf(ar[r], CE, brc[nt]));
                const float pz = 1.f + ez;
                const float pr = 1.f + er;
                const float d  = fast_rcp(pz * pr);
                const float zg = d * pr;                 // sigmoid(z-pre)
                const float rg = d * pz;                 // sigmoid(r-pre)
                const float hx = ax[r] + bx4[nt];
                const float hc = fmaxf(fmaf(rg, ah[r], hx), 0.f);   // ah includes b[1] fold
                const float ho = h32[nt][r];
                const float hn = fmaf(zg, ho - hc, hc);  // z*h + (1-z)*hc
                h32[nt][r] = hn;
                const int c = nt * 16 + n;
                if (nt < 3 || n < 2) {                   // c < 50
                    hs16[(quad * 4 + r) * H16S + c] = (_Float16)hn;
                }
            }
        }
        __syncthreads();   // single wave: trivial barrier, orders h16 write -> next read
    }

    // ---- epilogue: out[b] = h_T @ Wd + bd (exact f32 h) ----
    #pragma unroll
    for (int nt = 0; nt < 4; ++nt) {
        const int c = nt * 16 + n;
        if (c < UNITS) {
            #pragma unroll
            for (int r = 0; r < 4; ++r)
                hs32[(quad * 4 + r) * H32S + c] = h32[nt][r];
        }
    }
    __syncthreads();
    if (lane < NB) {
        float acc = bd[0];
        #pragma unroll
        for (int u = 0; u < UNITS; ++u)
            acc = fmaf(hs32[lane * H32S + u], Wd[u], acc);
        out[b0 + lane] = acc;
    }
}

extern "C" void kernel_launch(void* const* d_in, const int* in_sizes, int n_in,
                              void* d_out, int out_size, void* d_ws, size_t ws_size,
                              hipStream_t stream) {
    const float* x    = (const float*)d_in[0];
    const float* W    = (const float*)d_in[1];
    const float* U    = (const float*)d_in[2];
    const float* bv   = (const float*)d_in[3];
    const float* Wd   = (const float*)d_in[4];
    const float* bd   = (const float*)d_in[5];
    float* out = (float*)d_out;

    dim3 grid(BATCH / NB);    // 256 blocks -> 1 wave per CU
    dim3 block(64);           // exactly one wave
    gru_wave<<<grid, block, 0, stream>>>(x, W, U, bv, Wd, bd, out);
}

// Round 4
// 272.680 us; speedup vs baseline: 1.3055x; 1.3055x over previous
//
#include <hip/hip_runtime.h>
#include <math.h>

typedef _Float16 v8h __attribute__((ext_vector_type(8)));
typedef float v4f __attribute__((ext_vector_type(4)));

#define UNITS    50
#define K3       150
#define FDIM     64
#define TSTEPS   128
#define BATCH    4096
#define NB       16     // batch rows per block tile (MFMA M)
#define H16S     72     // halves per h row (50 h + slot50=1.0 + pad); 144 B stride, 16B-aligned
#define H32S     52

#if __has_builtin(__builtin_amdgcn_exp2f)
__device__ __forceinline__ float fast_exp2(float x) { return __builtin_amdgcn_exp2f(x); }
#else
__device__ __forceinline__ float fast_exp2(float x) { return exp2f(x); }
#endif
#if __has_builtin(__builtin_amdgcn_rcpf)
__device__ __forceinline__ float fast_rcp(float x) { return __builtin_amdgcn_rcpf(x); }
#else
__device__ __forceinline__ float fast_rcp(float x) { return 1.0f / x; }
#endif

// 4 waves per block, one 16-batch tile per block. Wave nt owns u-columns
// nt*16..nt*16+15 and computes ALL THREE gates for them -> Z/R/HX/HH stay
// lane- and register-aligned (C layout row=quad*4+reg, col=lane&15), gate math
// is register-local. Waves couple only through the f16 h exchange (ping-pong
// LDS buffers, one barrier per step). MFMA issue is spread across all 4 SIMDs
// (12 MFMAs/wave/step instead of 48 on one SIMD).
__global__ __launch_bounds__(256, 1)
void gru_4w(const float* __restrict__ x, const float* __restrict__ W,
            const float* __restrict__ U, const float* __restrict__ bv,
            const float* __restrict__ Wd, const float* __restrict__ bd,
            float* __restrict__ out) {
    __shared__ _Float16 hs16[2][NB * H16S];   // ping-pong h state (f16)
    __shared__ float    hs32[NB * H32S];      // epilogue only

    const int tid  = threadIdx.x;
    const int nt   = tid >> 6;          // wave id = ntile (wave-uniform)
    const int lane = tid & 63;
    const int n    = lane & 15;
    const int quad = lane >> 4;
    const int b0   = blockIdx.x * NB;
    const int c    = nt * 16 + n;       // this lane's unit column (>=50 for tail of wave 3)

    // ---- init both h buffers: zeros, constant 1.0 at slot u=50 (bias-fold row) ----
    for (int i = tid; i < NB * H16S; i += 256) {
        _Float16 v = ((i % H16S) == 50) ? (_Float16)1.f : (_Float16)0.f;
        hs16[0][i] = v;
        hs16[1][i] = v;
    }

    // ---- B fragments for this wave's ntile (VGPR-resident whole kernel) ----
    // combined K rows: 0..63 = W, 64..113 = U, 114 = b[1] h-col fold, rest 0
    v8h Bz[4], Br[4], Bh[4];
    #pragma unroll
    for (int kt = 0; kt < 4; ++kt) {
        v8h fz, fr, fh;
        #pragma unroll
        for (int j = 0; j < 8; ++j) {
            const int k = kt * 32 + quad * 8 + j;
            float vz = 0.f, vr = 0.f, vh = 0.f;
            if (c < UNITS) {
                if (k < FDIM) {
                    vz = W[k * K3 + c];
                    vr = W[k * K3 + 50 + c];
                    vh = W[k * K3 + 100 + c];
                } else if (k < FDIM + UNITS) {
                    const int ur = k - FDIM;
                    vz = U[ur * K3 + c];
                    vr = U[ur * K3 + 50 + c];
                    vh = U[ur * K3 + 100 + c];
                } else if (k == FDIM + UNITS) {
                    vh = bv[250 + c];           // b[1] h-col via h-slot u=50 == 1.0
                }
            }
            fz[j] = (_Float16)vz; fr[j] = (_Float16)vr; fh[j] = (_Float16)vh;
        }
        Bz[kt] = fz; Br[kt] = fr; Bh[kt] = fh;
    }

    // ---- sigmoid-folded bias constants for this lane's column ----
    const float CE = -1.44269504f;      // sigmoid(a) = 1 / (1 + 2^(CE*a))
    float bzc = 0.f, brc = 0.f, bx = 0.f;
    if (c < UNITS) {
        bzc = CE * (bv[c]      + bv[150 + c]);
        brc = CE * (bv[50 + c] + bv[200 + c]);
        bx  = bv[100 + c];
    }

    // f32 h state in registers: h32[r] = h[m=quad*4+r][u=c]
    v4f h32 = {0.f, 0.f, 0.f, 0.f};

    // ---- x prefetch for t=0 (lane covers batch row b0+n, k=quad*8..+7, +32) ----
    const float* xbase = x + ((size_t)(b0 + n) * TSTEPS) * FDIM + quad * 8;
    v4f px0 = *(const v4f*)(xbase + 0);
    v4f px1 = *(const v4f*)(xbase + 4);
    v4f px2 = *(const v4f*)(xbase + 32);
    v4f px3 = *(const v4f*)(xbase + 36);

    __syncthreads();

    for (int t = 0; t < TSTEPS; ++t) {
        const _Float16* hrd = hs16[t & 1];
        _Float16*       hwr = hs16[(t + 1) & 1];

        // A fragments: x part from regs, h part from LDS
        v8h A0, A1;
        #pragma unroll
        for (int j = 0; j < 4; ++j) {
            A0[j]     = (_Float16)px0[j];
            A0[j + 4] = (_Float16)px1[j];
            A1[j]     = (_Float16)px2[j];
            A1[j + 4] = (_Float16)px3[j];
        }
        v8h A2 = *(const v8h*)(&hrd[n * H16S + quad * 8]);       // k 64..95  (h 0..31)
        v8h A3 = *(const v8h*)(&hrd[n * H16S + 32 + quad * 8]);  // k 96..127 (h 32..49, 1.0, 0s)

        if (t + 1 < TSTEPS) {
            const float* xp = xbase + (size_t)(t + 1) * FDIM;
            px0 = *(const v4f*)(xp + 0);
            px1 = *(const v4f*)(xp + 4);
            px2 = *(const v4f*)(xp + 32);
            px3 = *(const v4f*)(xp + 36);
        }

        const v4f zero4 = {0.f, 0.f, 0.f, 0.f};
        // x-dependent MFMAs first (ready from regs), h-dependent after
        v4f ax = {bx, bx, bx, bx};
        v4f az = __builtin_amdgcn_mfma_f32_16x16x32_f16(A0, Bz[0], zero4, 0, 0, 0);
        az     = __builtin_amdgcn_mfma_f32_16x16x32_f16(A1, Bz[1], az,    0, 0, 0);
        v4f ar = __builtin_amdgcn_mfma_f32_16x16x32_f16(A0, Br[0], zero4, 0, 0, 0);
        ar     = __builtin_amdgcn_mfma_f32_16x16x32_f16(A1, Br[1], ar,    0, 0, 0);
        ax     = __builtin_amdgcn_mfma_f32_16x16x32_f16(A0, Bh[0], ax,    0, 0, 0);
        ax     = __builtin_amdgcn_mfma_f32_16x16x32_f16(A1, Bh[1], ax,    0, 0, 0);
        az     = __builtin_amdgcn_mfma_f32_16x16x32_f16(A2, Bz[2], az,    0, 0, 0);
        az     = __builtin_amdgcn_mfma_f32_16x16x32_f16(A3, Bz[3], az,    0, 0, 0);
        ar     = __builtin_amdgcn_mfma_f32_16x16x32_f16(A2, Br[2], ar,    0, 0, 0);
        ar     = __builtin_amdgcn_mfma_f32_16x16x32_f16(A3, Br[3], ar,    0, 0, 0);
        v4f ah = __builtin_amdgcn_mfma_f32_16x16x32_f16(A2, Bh[2], zero4, 0, 0, 0);
        ah     = __builtin_amdgcn_mfma_f32_16x16x32_f16(A3, Bh[3], ah,    0, 0, 0);

        // register-local gate math: 4 rows (m = quad*4 + r)
        #pragma unroll
        for (int r = 0; r < 4; ++r) {
            const float ez = fast_exp2(fmaf(az[r], CE, bzc));
            const float er = fast_exp2(fmaf(ar[r], CE, brc));
            const float pz = 1.f + ez;
            const float pr = 1.f + er;
            const float d  = fast_rcp(pz * pr);
            const float zg = d * pr;                 // sigmoid(z-pre)
            const float rg = d * pz;                 // sigmoid(r-pre)
            const float hc = fmaxf(fmaf(rg, ah[r], ax[r]), 0.f);  // ah includes b[1]
            const float hn = fmaf(zg, h32[r] - hc, hc);           // z*h + (1-z)*hc
            h32[r] = hn;
            if (c < UNITS)
                hwr[(quad * 4 + r) * H16S + c] = (_Float16)hn;
        }
        __syncthreads();   // orders h writes (t+1 buf) vs next step's reads
    }

    // ---- epilogue: out[b] = h_T @ Wd + bd (exact f32 h) ----
    if (c < UNITS) {
        #pragma unroll
        for (int r = 0; r < 4; ++r)
            hs32[(quad * 4 + r) * H32S + c] = h32[r];
    }
    __syncthreads();
    if (tid < NB) {
        float acc = bd[0];
        #pragma unroll
        for (int u = 0; u < UNITS; ++u)
            acc = fmaf(hs32[tid * H32S + u], Wd[u], acc);
        out[b0 + tid] = acc;
    }
}

extern "C" void kernel_launch(void* const* d_in, const int* in_sizes, int n_in,
                              void* d_out, int out_size, void* d_ws, size_t ws_size,
                              hipStream_t stream) {
    const float* x    = (const float*)d_in[0];
    const float* W    = (const float*)d_in[1];
    const float* U    = (const float*)d_in[2];
    const float* bv   = (const float*)d_in[3];
    const float* Wd   = (const float*)d_in[4];
    const float* bd   = (const float*)d_in[5];
    float* out = (float*)d_out;

    dim3 grid(BATCH / NB);    // 256 blocks -> 1 per CU
    dim3 block(256);          // 4 waves, one per SIMD
    gru_4w<<<grid, block, 0, stream>>>(x, W, U, bv, Wd, bd, out);
}